// Round 1
// baseline (153.463 us; speedup 1.0000x reference)
//
#include <hip/hip_runtime.h>

#define NB 256
#define NA 64
#define NG 978
#define CELL_IN 978
#define DOSE_IN 12
#define GLOBAL_F 306
#define EXP_IN 434
#define NE 4

// ---- workspace layout (float offsets) ----
// v is stored h-VECTORIZED + gene-transposed:
//   v4[tile16][e4][q=h/4 (32)][g64][4h]   float4 per (q,g), 1KB coalesced per wave
// element (t,e,q,g,j) at WS_V + (t*4+e)*8192 + q*256 + g*4 + j
#define WS_SEL 0                       // [256][4] : e1, e2, gate1, gate2
#define WS_U   (WS_SEL + NB*4)         // [256][2][128]
#define WS_V   (WS_U + NB*256)         // 16*4*32*64*4 = 524288 floats
// total ~591k floats ~2.4 MB

#define A_BLOCKS 256                   // 16 tiles x 4 experts x 4 h-quarters
#define AB_GRID  (NB + A_BLOCKS)       // 512 blocks -> 2 blocks/CU everywhere

__device__ __forceinline__ float wave_reduce(float p) {
    #pragma unroll
    for (int off = 32; off > 0; off >>= 1) p += __shfl_down(p, off, 64);
    return p;
}

__device__ __forceinline__ float rfl(float x) {
    return __int_as_float(__builtin_amdgcn_readfirstlane(__float_as_int(x)));
}

// ---------------------------------------------------------------------------
// AB: blocks [0,256): per-batch pipeline (r11 verbatim — proven).
//     blocks [256,512): v4 producer, one (64-gene tile, expert, h-quarter)
//     per block. Thread = (khalf2, slice8, g64): 4 h-cols, float4 weights.
// ---------------------------------------------------------------------------
__global__ __launch_bounds__(1024) void ab_kernel(
    const float* __restrict__ drug, const float* __restrict__ gex,
    const float* __restrict__ idose,
    const float* __restrict__ cW1, const float* __restrict__ cb1,
    const float* __restrict__ cW2, const float* __restrict__ cb2,
    const float* __restrict__ cW3, const float* __restrict__ cb3,
    const float* __restrict__ dW1, const float* __restrict__ db1,
    const float* __restrict__ dW2, const float* __restrict__ db2,
    const float* __restrict__ gW1, const float* __restrict__ gb1,
    const float* __restrict__ gW2, const float* __restrict__ gb2,
    const float* __restrict__ eW1, const float* __restrict__ eb1,
    const float* __restrict__ gene,
    float* __restrict__ ws, float* __restrict__ cell_out)
{
    __shared__ float s_gex[CELL_IN];
    __shared__ float s_g[GLOBAL_F];
    __shared__ float s_h1[200];
    __shared__ float s_h2[100];
    __shared__ float s_gh[128];
    __shared__ float s_d1[64];
    __shared__ int   s_isel[2];
    __shared__ float s_part[16 * 200];
    __shared__ float s_pu[32 * 128];
    __shared__ float s_gene[64 * 129];   // a-part only (padded)

    const int blk = blockIdx.x, tid = threadIdx.x;

    if (blk >= NB) {
        // ===== a-part: v4[tile][e][q][g][4], (tile,e,hq) per block =====
        const int ablk = blk - NB;                 // 0..255
        const int tile = ablk >> 4, e = (ablk >> 2) & 3, hq = ablk & 3;

        for (int i = tid; i < 64 * 128; i += 1024) {
            int gl = i >> 7, k = i & 127;
            int g = tile * 64 + gl;
            s_gene[gl * 129 + k] = (g < NG) ? gene[g * 128 + k] : 0.f;
        }
        __syncthreads();

        // thread -> (khalf, slice, g): 4 h-columns, 64 k each
        const int g_in  = tid & 63;
        const int slice = (tid >> 6) & 7;          // 8 slices x 4h = 32 h
        const int khalf = tid >> 9;                // 2-way k split
        const int h0 = hq * 32 + slice * 4;
        const float* wbase = eW1
            + ((size_t)e * EXP_IN + GLOBAL_F + khalf * 64) * 128 + h0;
        float4 acc = {0.f, 0.f, 0.f, 0.f};
        #pragma unroll 8
        for (int k = 0; k < 64; ++k) {
            float x = s_gene[g_in * 129 + khalf * 64 + k];   // padded: conflict-free
            float4 w = *(const float4*)(wbase + (size_t)k * 128);
            acc.x += x * w.x; acc.y += x * w.y; acc.z += x * w.z; acc.w += x * w.w;
        }
        // reduce across khalf through s_pu [2][512][4]
        *(float4*)&s_pu[(khalf * 512 + slice * 64 + g_in) * 4] = acc;
        __syncthreads();
        if (khalf == 0) {
            float4 a0 = *(const float4*)&s_pu[(slice * 64 + g_in) * 4];
            float4 a1 = *(const float4*)&s_pu[(512 + slice * 64 + g_in) * 4];
            float4 r = {a0.x + a1.x, a0.y + a1.y, a0.z + a1.z, a0.w + a1.w};
            const int q = hq * 8 + slice;          // h = q*4 + j
            float* vout = ws + WS_V
                + ((size_t)(tile * 4 + e)) * 8192 + q * 256 + g_in * 4;
            *(float4*)vout = r;                    // lane=gene: 1KB coalesced
        }
        return;
    }

    // ==================== b-part: per-batch pipeline (r11 verbatim) ========
    const int b = blk;

    // ---- P0: stage gex; drug partials; dose layer1 ----
    if (tid < CELL_IN) s_gex[tid] = gex[b * CELL_IN + tid];
    {
        int row = tid >> 7, d = tid & 127;
        const float* p = drug + ((size_t)b * NA) * 128 + d;
        float acc = 0.f;
        #pragma unroll
        for (int i = 0; i < 8; ++i) acc += p[(size_t)(i * 8 + row) * 128];
        s_pu[row * 128 + d] = acc;
    }
    __syncthreads();
    if (tid < 128) {
        float a = 0.f;
        #pragma unroll
        for (int r = 0; r < 8; ++r) a += s_pu[r * 128 + tid];
        s_g[tid] = a;
    } else if (tid < 192) {
        int j = tid - 128;
        float acc = db1[j];
        #pragma unroll
        for (int i = 0; i < DOSE_IN; ++i)
            acc += idose[b * DOSE_IN + i] * dW1[i * 64 + j];
        s_d1[j] = fmaxf(acc, 0.f);
    }
    __syncthreads();
    if (tid < 128) {
        float acc = db2[tid];
        #pragma unroll 8
        for (int i = 0; i < 64; ++i) acc += s_d1[i] * dW2[i * 128 + tid];
        s_g[178 + tid] = fmaxf(acc, 0.f);
    }
    __syncthreads();

    // ---- P1: cell1 978->200, 16-way K-split, float4 ----
    {
        int q = tid & 63, ks = tid >> 6;
        if (q < 50) {
            int i0 = ks * 62, i1 = min(i0 + 62, CELL_IN);
            float4 acc = {0.f, 0.f, 0.f, 0.f};
            #pragma unroll 4
            for (int i = i0; i < i1; ++i) {
                float4 w = *(const float4*)(cW1 + (size_t)i * 200 + 4 * q);
                float x = s_gex[i];
                acc.x += x * w.x; acc.y += x * w.y; acc.z += x * w.z; acc.w += x * w.w;
            }
            *(float4*)(&s_part[ks * 200 + 4 * q]) = acc;
        }
    }
    __syncthreads();
    if (tid < 200) {
        float a = cb1[tid];
        #pragma unroll
        for (int ks = 0; ks < 16; ++ks) a += s_part[ks * 200 + tid];
        s_h1[tid] = fmaxf(a, 0.f);
    }
    __syncthreads();

    // ---- P2: cell2 200->100, 16-way K-split, float4 ----
    {
        int q = tid & 31, ks = tid >> 5;
        if (q < 25 && ks < 16) {
            int i0 = ks * 13, i1 = min(i0 + 13, 200);
            float4 acc = {0.f, 0.f, 0.f, 0.f};
            #pragma unroll
            for (int i = i0; i < i1; ++i) {
                float4 w = *(const float4*)(cW2 + (size_t)i * 100 + 4 * q);
                float x = s_h1[i];
                acc.x += x * w.x; acc.y += x * w.y; acc.z += x * w.z; acc.w += x * w.w;
            }
            *(float4*)(&s_part[ks * 100 + 4 * q]) = acc;
        }
    }
    __syncthreads();
    if (tid < 100) {
        float a = cb2[tid];
        #pragma unroll
        for (int ks = 0; ks < 16; ++ks) a += s_part[ks * 100 + tid];
        s_h2[tid] = fmaxf(a, 0.f);
    }
    __syncthreads();

    // ---- P3: cell3 100->50, 8-way K-split ----
    {
        int j = tid & 63, ks = tid >> 6;
        if (j < 50 && ks < 8) {
            int i0 = ks * 13, i1 = min(i0 + 13, 100);
            float acc = 0.f;
            #pragma unroll
            for (int i = i0; i < i1; ++i) acc += s_h2[i] * cW3[i * 50 + j];
            s_part[ks * 64 + j] = acc;
        }
    }
    __syncthreads();
    if (tid < 50) {
        float a = cb3[tid];
        #pragma unroll
        for (int ks = 0; ks < 8; ++ks) a += s_part[ks * 64 + tid];
        float r = fmaxf(a, 0.f);
        s_g[128 + tid] = r;
        cell_out[b * 50 + tid] = r;
    }
    __syncthreads();

    // ---- P4: gate1 306->128, 16-way K-split, float4 ----
    {
        int q = tid & 31, ks = tid >> 5;
        if (ks < 16) {
            int i0 = ks * 20, i1 = min(i0 + 20, GLOBAL_F);
            float4 acc = {0.f, 0.f, 0.f, 0.f};
            #pragma unroll
            for (int i = i0; i < i1; ++i) {
                float4 w = *(const float4*)(gW1 + (size_t)i * 128 + 4 * q);
                float x = s_g[i];
                acc.x += x * w.x; acc.y += x * w.y; acc.z += x * w.z; acc.w += x * w.w;
            }
            *(float4*)(&s_part[ks * 128 + 4 * q]) = acc;
        }
    }
    __syncthreads();
    if (tid < 128) {
        float a = gb1[tid];
        #pragma unroll
        for (int ks = 0; ks < 16; ++ks) a += s_part[ks * 128 + tid];
        s_gh[tid] = fmaxf(a, 0.f);
    }
    __syncthreads();

    // ---- P5: logits + top-2 softmax -> s_isel, ws sel ----
    if (tid < 64) {
        float h0 = s_gh[tid], h1 = s_gh[tid + 64];
        float logit[NE];
        #pragma unroll
        for (int j = 0; j < NE; ++j) {
            float p = h0 * gW2[tid * NE + j] + h1 * gW2[(tid + 64) * NE + j];
            p = wave_reduce(p);
            logit[j] = p + gb2[j];
        }
        if (tid == 0) {
            int i1 = 0; float v1 = logit[0];
            #pragma unroll
            for (int i = 1; i < NE; ++i) if (logit[i] > v1) { v1 = logit[i]; i1 = i; }
            int i2 = -1; float v2 = -__builtin_inff();
            #pragma unroll
            for (int i = 0; i < NE; ++i) {
                if (i == i1) continue;
                if (logit[i] > v2) { v2 = logit[i]; i2 = i; }
            }
            float ex = __expf(v2 - v1);
            float inv = 1.f / (1.f + ex);
            s_isel[0] = i1; s_isel[1] = i2;
            ws[WS_SEL + b * 4 + 0] = (float)i1;
            ws[WS_SEL + b * 4 + 1] = (float)i2;
            ws[WS_SEL + b * 4 + 2] = inv;
            ws[WS_SEL + b * 4 + 3] = ex * inv;
        }
    }
    __syncthreads();

    // ---- P6: u for the 2 ACTIVE experts, 16-way K-split, float4 ----
    {
        int es = tid >> 9, ks = (tid >> 5) & 15, h4 = tid & 31;
        int e = s_isel[es];
        int i0 = ks * 20, i1 = min(i0 + 20, GLOBAL_F);
        const float* wp = eW1 + (size_t)e * EXP_IN * 128 + 4 * h4;
        float4 acc = {0.f, 0.f, 0.f, 0.f};
        #pragma unroll
        for (int i = i0; i < i1; ++i) {
            float4 w = *(const float4*)(wp + (size_t)i * 128);
            float x = s_g[i];
            acc.x += x * w.x; acc.y += x * w.y; acc.z += x * w.z; acc.w += x * w.w;
        }
        *(float4*)(&s_pu[(es * 16 + ks) * 128 + 4 * h4]) = acc;
    }
    __syncthreads();
    if (tid < 256) {
        int es = tid >> 7, h = tid & 127;
        int e = s_isel[es];
        float a = eb1[e * 128 + h];
        #pragma unroll
        for (int ks = 0; ks < 16; ++ks) a += s_pu[(es * 16 + ks) * 128 + h];
        ws[WS_U + (size_t)b * 256 + es * 128 + h] = a;
    }
}

// ---------------------------------------------------------------------------
// C: epilogue over v4. No LDS. sel/u/w2 are wave-uniform -> SGPR scalar
// loads; v reads are float4, 1KB coalesced per wave-load (4x fewer VMEM).
// grid = 256 b x 4 quads, 256 thr; wave -> 64-gene tile, lane -> gene.
// ---------------------------------------------------------------------------
__global__ __launch_bounds__(256) void c_kernel(
    const float* __restrict__ eW2, const float* __restrict__ eb2,
    const float* __restrict__ ws, float* __restrict__ pred)
{
    const int b = blockIdx.x >> 2, quad = blockIdx.x & 3, tid = threadIdx.x;

    const float* sel = ws + WS_SEL + (size_t)b * 4;
    const int ea = __builtin_amdgcn_readfirstlane((int)sel[0]);
    const int eb = __builtin_amdgcn_readfirstlane((int)sel[1]);
    const float gA = rfl(sel[2]);
    const float gB = rfl(sel[3]);
    const float bA = eb2[ea], bB = eb2[eb];

    const float* pu = ws + WS_U + (size_t)b * 256;   // uniform base -> s_load
    const float* wA = eW2 + ea * 128;
    const float* wB = eW2 + eb * 128;

    const int wv = tid >> 6, lane = tid & 63;
    const int tile = quad * 4 + wv;
    const float* vA = ws + WS_V + ((size_t)(tile * 4 + ea)) * 8192 + lane * 4;
    const float* vB = ws + WS_V + ((size_t)(tile * 4 + eb)) * 8192 + lane * 4;

    float dA = 0.f, dB = 0.f;
    #pragma unroll 8
    for (int q = 0; q < 32; ++q) {
        float4 va = *(const float4*)(vA + q * 256);
        float4 ua = *(const float4*)(pu + q * 4);
        float4 wa = *(const float4*)(wA + q * 4);
        dA += fmaxf(ua.x + va.x, 0.f) * wa.x + fmaxf(ua.y + va.y, 0.f) * wa.y
            + fmaxf(ua.z + va.z, 0.f) * wa.z + fmaxf(ua.w + va.w, 0.f) * wa.w;
        float4 vb = *(const float4*)(vB + q * 256);
        float4 ub = *(const float4*)(pu + 128 + q * 4);
        float4 wb = *(const float4*)(wB + q * 4);
        dB += fmaxf(ub.x + vb.x, 0.f) * wb.x + fmaxf(ub.y + vb.y, 0.f) * wb.y
            + fmaxf(ub.z + vb.z, 0.f) * wb.z + fmaxf(ub.w + vb.w, 0.f) * wb.w;
    }
    const int g = tile * 64 + lane;
    if (g < NG) pred[(size_t)b * NG + g] = gA * (dA + bA) + gB * (dB + bB);
}

// ---------------------------------------------------------------------------
extern "C" void kernel_launch(void* const* d_in, const int* in_sizes, int n_in,
                              void* d_out, int out_size, void* d_ws, size_t ws_size,
                              hipStream_t stream) {
    const float* drug  = (const float*)d_in[0];
    const float* gex   = (const float*)d_in[1];
    const float* idose = (const float*)d_in[2];
    const float* cW1 = (const float*)d_in[3];  const float* cb1 = (const float*)d_in[4];
    const float* cW2 = (const float*)d_in[5];  const float* cb2 = (const float*)d_in[6];
    const float* cW3 = (const float*)d_in[7];  const float* cb3 = (const float*)d_in[8];
    const float* dW1 = (const float*)d_in[9];  const float* db1 = (const float*)d_in[10];
    const float* dW2 = (const float*)d_in[11]; const float* db2 = (const float*)d_in[12];
    const float* gene = (const float*)d_in[13];
    const float* gW1 = (const float*)d_in[14]; const float* gb1 = (const float*)d_in[15];
    const float* gW2 = (const float*)d_in[16]; const float* gb2 = (const float*)d_in[17];
    const float* eW1 = (const float*)d_in[18]; const float* eb1 = (const float*)d_in[19];
    const float* eW2 = (const float*)d_in[20]; const float* eb2 = (const float*)d_in[21];

    float* ws   = (float*)d_ws;
    float* out  = (float*)d_out;
    float* pred = out;               // [B, G]
    float* cell = out + NB * NG;     // [B, 50]

    ab_kernel<<<AB_GRID, 1024, 0, stream>>>(drug, gex, idose,
        cW1, cb1, cW2, cb2, cW3, cb3, dW1, db1, dW2, db2,
        gW1, gb1, gW2, gb2, eW1, eb1, gene, ws, cell);
    c_kernel<<<NB * 4, 256, 0, stream>>>(eW2, eb2, ws, pred);
}